// Round 4
// baseline (153.003 us; speedup 1.0000x reference)
//
#include <hip/hip_runtime.h>
#include <cstdint>
#include <cstddef>

typedef __bf16 bf16;
typedef __bf16 bf16x2 __attribute__((ext_vector_type(2)));
typedef __bf16 bf16x4 __attribute__((ext_vector_type(4)));
typedef __bf16 bf16x8 __attribute__((ext_vector_type(8)));
typedef float  f32x4  __attribute__((ext_vector_type(4)));
typedef float  f32x16 __attribute__((ext_vector_type(16)));

// global -> LDS direct (16B/lane, dest = wave-uniform base + lane*16)
#define G2L(src, dst)                                                          \
  __builtin_amdgcn_global_load_lds(                                            \
      (const __attribute__((address_space(1))) unsigned int*)(src),            \
      (__attribute__((address_space(3))) unsigned int*)(dst), 16, 0, 0)

// ---------------- convert f32 -> bf16 (n multiple of 8) ----------------
__global__ void k_f32_to_bf16(const float* __restrict__ in, bf16* __restrict__ out, int n) {
  int i = (blockIdx.x * blockDim.x + threadIdx.x) * 8;
  if (i >= n) return;
  float4 a = *(const float4*)(in + i);
  float4 b = *(const float4*)(in + i + 4);
  bf16x8 o;
  o[0] = (bf16)a.x; o[1] = (bf16)a.y; o[2] = (bf16)a.z; o[3] = (bf16)a.w;
  o[4] = (bf16)b.x; o[5] = (bf16)b.y; o[6] = (bf16)b.z; o[7] = (bf16)b.w;
  *(bf16x8*)(out + i) = o;
}

// ---------------- transpose f32[R][C] -> bf16[C][R] ----------------
__global__ void k_transpose_f32_bf16(const float* __restrict__ in, bf16* __restrict__ out,
                                     int R, int C) {
  __shared__ float tile[32][33];
  int c0 = blockIdx.x * 32, r0 = blockIdx.y * 32;
  int tx = threadIdx.x & 31, ty = threadIdx.x >> 5;  // 32 x 8
#pragma unroll
  for (int i = 0; i < 32; i += 8)
    tile[ty + i][tx] = in[(size_t)(r0 + ty + i) * C + c0 + tx];
  __syncthreads();
#pragma unroll
  for (int i = 0; i < 32; i += 8)
    out[(size_t)(c0 + ty + i) * R + r0 + tx] = (bf16)tile[tx][ty + i];
}

// ---------------- RoPE tables: cos/sin [T][32] fp32 ----------------
__global__ void k_rope_tables(float* __restrict__ cosT, float* __restrict__ sinT, int total) {
  int i = blockIdx.x * blockDim.x + threadIdx.x;
  if (i >= total) return;
  int t = i >> 5, j = i & 31;
  float inv = powf(10000.0f, -(float)j * (1.0f / 32.0f));
  float f = (float)t * inv;
  cosT[i] = cosf(f);
  sinT[i] = sinf(f);
}

// ---------------- RoPE q,k: qkv[4096][3072] -> qr,kr [B][H][T][64] ----------------
// q is pre-scaled by 0.125 (exact pow2 in bf16) so flash needs no scale.
__global__ void k_rope_qk(const bf16* __restrict__ qkv, const float* __restrict__ cosT,
                          const float* __restrict__ sinT, bf16* __restrict__ qr,
                          bf16* __restrict__ kr) {
  int i = blockIdx.x * blockDim.x + threadIdx.x;  // B*T*H*32 = 2^21
  int j = i & 31;
  int h = (i >> 5) & 15;
  int t = (i >> 9) & 2047;
  int b = i >> 20;
  size_t base = (size_t)(b * 2048 + t) * 3072;
  float c = cosT[t * 32 + j], s = sinT[t * 32 + j];
  float qlo = (float)qkv[base + h * 64 + j];
  float qhi = (float)qkv[base + h * 64 + j + 32];
  float klo = (float)qkv[base + 1024 + h * 64 + j];
  float khi = (float)qkv[base + 1024 + h * 64 + j + 32];
  size_t ob = ((size_t)(b * 16 + h) * 2048 + t) * 64;
  qr[ob + j]      = (bf16)((qlo * c - qhi * s) * 0.125f);
  qr[ob + j + 32] = (bf16)((qhi * c + qlo * s) * 0.125f);
  kr[ob + j]      = (bf16)(klo * c - khi * s);
  kr[ob + j + 32] = (bf16)(khi * c + klo * s);
}

// ---------------- V scatter: qkv v-section -> vt [B][H][64][T] ----------------
__global__ void k_v_scatter(const bf16* __restrict__ qkv, bf16* __restrict__ vt) {
  __shared__ bf16 tile[64][66];
  int bh = blockIdx.y;           // 0..31
  int t0 = blockIdx.x * 64;
  int b = bh >> 4, h = bh & 15;
  int tt = threadIdx.x >> 2, c4 = (threadIdx.x & 3) * 16;
  const bf16* src = qkv + (size_t)(b * 2048 + t0 + tt) * 3072 + 2048 + h * 64 + c4;
  bf16x8 v0 = *(const bf16x8*)src;
  bf16x8 v1 = *(const bf16x8*)(src + 8);
#pragma unroll
  for (int j = 0; j < 8; j++) { tile[tt][c4 + j] = v0[j]; tile[tt][c4 + 8 + j] = v1[j]; }
  __syncthreads();
  int d = threadIdx.x >> 2, tc0 = (threadIdx.x & 3) * 16;
  bf16x8 o0, o1;
#pragma unroll
  for (int j = 0; j < 8; j++) { o0[j] = tile[tc0 + j][d]; o1[j] = tile[tc0 + 8 + j][d]; }
  bf16* dst = vt + ((size_t)bh * 64 + d) * 2048 + t0 + tc0;
  *(bf16x8*)dst = o0;
  *(bf16x8*)(dst + 8) = o1;
}

// ---------------- GEMM (m97 structure): C[M][N] = A[M][K] * Bt[N][K]^T ----------------
template <int OUTF32>
__global__ __launch_bounds__(256) void k_gemm_bt(const bf16* __restrict__ A,
                                                 const bf16* __restrict__ Bt,
                                                 float* __restrict__ Cf, bf16* __restrict__ Cb,
                                                 int M, int N, int K) {
  __shared__ __align__(16) bf16 sA[128 * 64];
  __shared__ __align__(16) bf16 sB[128 * 64];
  int m0 = blockIdx.y * 128, n0 = blockIdx.x * 128;
  int t = threadIdx.x, lane = t & 63, w = t >> 6;
  int wr = w >> 1, wc = w & 1;
  int lr = lane & 15, q2 = lane >> 4;
  int srow8 = lane >> 3, pc8 = lane & 7;
  f32x4 acc[4][4] = {};
  for (int k0 = 0; k0 < K; k0 += 64) {
#pragma unroll
    for (int is = 0; is < 4; is++) {
      int r = w * 32 + is * 8 + srow8;
      int lc = pc8 ^ (r & 7);
      G2L(A + (size_t)(m0 + r) * K + k0 + lc * 8, &sA[(w * 32 + is * 8) * 64]);
    }
#pragma unroll
    for (int is = 0; is < 4; is++) {
      int r = w * 32 + is * 8 + srow8;
      int lc = pc8 ^ (r & 7);
      G2L(Bt + (size_t)(n0 + r) * K + k0 + lc * 8, &sB[(w * 32 + is * 8) * 64]);
    }
    __syncthreads();
#pragma unroll
    for (int ch = 0; ch < 2; ch++) {
      bf16x8 af[4], bfr[4];
#pragma unroll
      for (int i = 0; i < 4; i++) {
        int r = wr * 64 + i * 16 + lr;
        af[i] = *(const bf16x8*)&sA[r * 64 + (((ch * 4 + q2) ^ (r & 7)) * 8)];
      }
#pragma unroll
      for (int i = 0; i < 4; i++) {
        int r = wc * 64 + i * 16 + lr;
        bfr[i] = *(const bf16x8*)&sB[r * 64 + (((ch * 4 + q2) ^ (r & 7)) * 8)];
      }
#pragma unroll
      for (int mi = 0; mi < 4; mi++)
#pragma unroll
        for (int ni = 0; ni < 4; ni++)
          acc[mi][ni] = __builtin_amdgcn_mfma_f32_16x16x32_bf16(af[mi], bfr[ni], acc[mi][ni], 0, 0, 0);
    }
    __syncthreads();
  }
  int row_base = m0 + wr * 64, col_base = n0 + wc * 64;
#pragma unroll
  for (int mi = 0; mi < 4; mi++)
#pragma unroll
    for (int ni = 0; ni < 4; ni++) {
      int col = col_base + ni * 16 + lr;
#pragma unroll
      for (int r = 0; r < 4; r++) {
        int row = row_base + mi * 16 + q2 * 4 + r;
        float v = acc[mi][ni][r];
        if (OUTF32) Cf[(size_t)row * N + col] = v;
        else        Cb[(size_t)row * N + col] = (bf16)v;
      }
    }
}

// ---------------- causal flash attention: 32x32x16 MFMA, QBLK=128, 4 waves ----------------
// qr,kr: [BH][T][64]; vt: [BH][64][T]; out (attn): [B][T][1024] bf16
// Fold: block handles q-blocks {pair, 15-pair} (128 q each) -> 34 kt-iters/block.
// Wave w owns q-cols [qb*128 + w*32, +32). Swapped MFMA: S^T = K·Q^T so q is lane-local.
__global__ __launch_bounds__(256) void k_flash(const bf16* __restrict__ qr,
                                               const bf16* __restrict__ kr,
                                               const bf16* __restrict__ vt,
                                               bf16* __restrict__ out) {
  const int T = 2048;
  int pair = blockIdx.x;   // 0..7
  int bh = blockIdx.y;     // 0..31
  int b = bh >> 4, h = bh & 15;
  __shared__ __align__(16) bf16 sK[2][64 * 64];
  __shared__ __align__(16) bf16 sV[2][64 * 64];
  __shared__ __align__(16) bf16 sP[4][32 * 68];   // per-wave, pad 64->68 (2-way free)
  int t = threadIdx.x, lane = t & 63, w = t >> 6;
  int q31 = lane & 31, hi = lane >> 5;
  int srow8 = lane >> 3, pc8 = lane & 7;
  bf16* Pw = &sP[w][0];

  const bf16* Kbh = kr + (size_t)bh * T * 64;
  const bf16* Vbh = vt + (size_t)bh * 64 * T;

  auto stage = [&](int buf, int kt) {
#pragma unroll
    for (int is = 0; is < 2; is++) {
      int r = w * 16 + is * 8 + srow8;
      int lc = pc8 ^ (r & 7);
      G2L(Kbh + (size_t)(kt * 64 + r) * 64 + lc * 8, &sK[buf][(w * 16 + is * 8) * 64]);
    }
#pragma unroll
    for (int is = 0; is < 2; is++) {
      int d = w * 16 + is * 8 + srow8;
      int lc = pc8 ^ (d & 7);
      G2L(Vbh + (size_t)d * T + kt * 64 + lc * 8, &sV[buf][(w * 16 + is * 8) * 64]);
    }
  };

  for (int sel = 0; sel < 2; sel++) {
    int qb = sel ? 15 - pair : pair;
    int nk = 2 * qb + 2;
    int qwb = qb * 128 + w * 32;    // wave q base
    int qg = qwb + q31;             // this lane's q row
    // Q B-frags (pre-scaled by 1/8): lane holds q-col qg, d = ks*16 + hi*8 + 0..7
    const bf16* qrow = qr + ((size_t)bh * T + qg) * 64 + hi * 8;
    bf16x8 qf[4];
#pragma unroll
    for (int ks = 0; ks < 4; ks++) qf[ks] = *(const bf16x8*)(qrow + ks * 16);
    f32x16 o0 = {}, o1 = {};
    float m = -1e30f, l = 0.f;

    stage(0, 0);
    for (int kt = 0; kt < nk; kt++) {
      int buf = kt & 1;
      if (kt + 1 < nk) {
        stage(buf ^ 1, kt + 1);
        asm volatile("s_waitcnt vmcnt(4)" ::: "memory");
      } else {
        asm volatile("s_waitcnt vmcnt(0)" ::: "memory");
      }
      __builtin_amdgcn_s_barrier();
      asm volatile("" ::: "memory");
      __builtin_amdgcn_sched_barrier(0);
      bool active = (kt * 64 <= qwb + 31);
      if (active) {
        const bf16* Kb = &sK[buf][0];
        const bf16* Vb = &sV[buf][0];
        // ---- S^T = K Q^T : two 32x32 tiles (kb), K-dim d=64 in 4 steps ----
        f32x16 s[2];
#pragma unroll
        for (int kb = 0; kb < 2; kb++) {
          f32x16 a = {};
          int krow = kb * 32 + q31;
#pragma unroll
          for (int ks = 0; ks < 4; ks++) {
            int ch = (ks * 2 + hi) ^ (krow & 7);
            bf16x8 kf = *(const bf16x8*)&Kb[krow * 64 + ch * 8];
            a = __builtin_amdgcn_mfma_f32_32x32x16_bf16(kf, qf[ks], a, 0, 0, 0);
          }
          s[kb] = a;
        }
        // ---- causal mask: needed when tile max k exceeds wave MIN q ----
        if (kt * 64 + 63 > qwb) {
          int thr = qg - kt * 64;  // mask if k_local > thr
#pragma unroll
          for (int kb = 0; kb < 2; kb++)
#pragma unroll
            for (int r = 0; r < 16; r++) {
              int koff = kb * 32 + (r & 3) + 8 * (r >> 2) + 4 * hi;
              if (koff > thr) s[kb][r] = -1e30f;
            }
        }
        // ---- lane-local online softmax (q = qg for both lane halves) ----
        float px = -1e30f;
#pragma unroll
        for (int kb = 0; kb < 2; kb++)
#pragma unroll
          for (int r = 0; r < 16; r++) px = fmaxf(px, s[kb][r]);
        px = fmaxf(px, __shfl_xor(px, 32, 64));
        float mn = fmaxf(m, px);
        float alpha = __expf(m - mn);
        m = mn;
        float rs = 0.f;
#pragma unroll
        for (int kb = 0; kb < 2; kb++)
#pragma unroll
          for (int r = 0; r < 16; r++) {
            float p = __expf(s[kb][r] - m);
            s[kb][r] = p;
            rs += p;
          }
        rs += __shfl_xor(rs, 32, 64);
        l = l * alpha + rs;
        // ---- P -> wave-private LDS: P[q][k], b64 writes (k groups of 4) ----
#pragma unroll
        for (int kb = 0; kb < 2; kb++)
#pragma unroll
          for (int g = 0; g < 4; g++) {
            bf16x4 pk;
            pk[0] = (bf16)s[kb][4 * g + 0];
            pk[1] = (bf16)s[kb][4 * g + 1];
            pk[2] = (bf16)s[kb][4 * g + 2];
            pk[3] = (bf16)s[kb][4 * g + 3];
            *(bf16x4*)&Pw[q31 * 68 + kb * 32 + 8 * g + 4 * hi] = pk;
          }
        // ---- rescale O ----
#pragma unroll
        for (int r = 0; r < 16; r++) { o0[r] *= alpha; o1[r] *= alpha; }
        // ---- O^T += V^T P^T : two 32x32 tiles (db), K-dim k=64 in 4 steps ----
#pragma unroll
        for (int ks = 0; ks < 4; ks++) {
          bf16x8 pb = *(const bf16x8*)&Pw[q31 * 68 + ks * 16 + hi * 8];
          {
            int drow = q31;
            int ch = (ks * 2 + hi) ^ (drow & 7);
            bf16x8 vf = *(const bf16x8*)&Vb[drow * 64 + ch * 8];
            o0 = __builtin_amdgcn_mfma_f32_32x32x16_bf16(vf, pb, o0, 0, 0, 0);
          }
          {
            int drow = 32 + q31;
            int ch = (ks * 2 + hi) ^ (drow & 7);
            bf16x8 vf = *(const bf16x8*)&Vb[drow * 64 + ch * 8];
            o1 = __builtin_amdgcn_mfma_f32_32x32x16_bf16(vf, pb, o1, 0, 0, 0);
          }
        }
      }
      asm volatile("" ::: "memory");
      __builtin_amdgcn_s_barrier();
      asm volatile("" ::: "memory");
    }
    // ---- epilogue: O^T[d][qg] -> out[b][qg][h*64+d], b64 stores ----
    float linv = 1.0f / l;
    bf16* orow = out + ((size_t)b * T + qg) * 1024 + h * 64;
#pragma unroll
    for (int g = 0; g < 4; g++) {
      bf16x4 v0, v1;
#pragma unroll
      for (int j = 0; j < 4; j++) {
        v0[j] = (bf16)(o0[4 * g + j] * linv);
        v1[j] = (bf16)(o1[4 * g + j] * linv);
      }
      *(bf16x4*)&orow[8 * g + 4 * hi]      = v0;
      *(bf16x4*)&orow[32 + 8 * g + 4 * hi] = v1;
    }
  }
}

// ---------------- launch ----------------
extern "C" void kernel_launch(void* const* d_in, const int* in_sizes, int n_in,
                              void* d_out, int out_size, void* d_ws, size_t ws_size,
                              hipStream_t stream) {
  const float* x     = (const float*)d_in[0];
  const float* Wqkv  = (const float*)d_in[1];
  const float* Wproj = (const float*)d_in[2];
  float* outp = (float*)d_out;
  const int B = 2, T = 2048, C = 1024;
  const int M = B * T;  // 4096

  char* ws = (char*)d_ws;
  size_t off = 0;
  auto alloc = [&](size_t bytes) {
    void* p = ws + off;
    off += (bytes + 255) & ~(size_t)255;
    return p;
  };
  bf16* xb     = (bf16*)alloc((size_t)M * C * 2);
  bf16* wqkvt  = (bf16*)alloc((size_t)3 * C * C * 2);
  bf16* wprojt = (bf16*)alloc((size_t)C * C * 2);
  float* cosT  = (float*)alloc((size_t)T * 32 * 4);
  float* sinT  = (float*)alloc((size_t)T * 32 * 4);
  bf16* qkv    = (bf16*)alloc((size_t)M * 3 * C * 2);
  bf16* qr     = (bf16*)alloc((size_t)M * C * 2);
  bf16* kr     = (bf16*)alloc((size_t)M * C * 2);
  bf16* vt     = (bf16*)alloc((size_t)M * C * 2);
  bf16* attn   = qkv;  // alias: qkv dead after rope/v_scatter

  k_f32_to_bf16<<<dim3(M * C / 8 / 256), dim3(256), 0, stream>>>(x, xb, M * C);
  k_transpose_f32_bf16<<<dim3(3 * C / 32, C / 32), dim3(256), 0, stream>>>(Wqkv, wqkvt, C, 3 * C);
  k_transpose_f32_bf16<<<dim3(C / 32, C / 32), dim3(256), 0, stream>>>(Wproj, wprojt, C, C);
  k_rope_tables<<<dim3(T * 32 / 256), dim3(256), 0, stream>>>(cosT, sinT, T * 32);
  k_gemm_bt<0><<<dim3(3 * C / 128, M / 128), dim3(256), 0, stream>>>(xb, wqkvt, (float*)nullptr, qkv, M, 3 * C, C);
  k_rope_qk<<<dim3((B * T * 16 * 32) / 256), dim3(256), 0, stream>>>(qkv, cosT, sinT, qr, kr);
  k_v_scatter<<<dim3(T / 64, 32), dim3(256), 0, stream>>>(qkv, vt);
  k_flash<<<dim3(8, 32), dim3(256), 0, stream>>>(qr, kr, vt, attn);
  k_gemm_bt<1><<<dim3(C / 128, M / 128), dim3(256), 0, stream>>>(attn, wprojt, outp, (bf16*)nullptr, M, C, C);
}

// Round 5
// 150.437 us; speedup vs baseline: 1.0171x; 1.0171x over previous
//
#include <hip/hip_runtime.h>
#include <cstdint>
#include <cstddef>

typedef __bf16 bf16;
typedef __bf16 bf16x2 __attribute__((ext_vector_type(2)));
typedef __bf16 bf16x4 __attribute__((ext_vector_type(4)));
typedef __bf16 bf16x8 __attribute__((ext_vector_type(8)));
typedef float  f32x4  __attribute__((ext_vector_type(4)));
typedef float  f32x16 __attribute__((ext_vector_type(16)));
typedef int    i32x4  __attribute__((ext_vector_type(4)));

// global -> LDS direct (16B/lane, dest = wave-uniform base + lane*16)
#define G2L(src, dst)                                                          \
  __builtin_amdgcn_global_load_lds(                                            \
      (const __attribute__((address_space(1))) unsigned int*)(src),            \
      (__attribute__((address_space(3))) unsigned int*)(dst), 16, 0, 0)

// ---------------- convert f32 -> bf16 (n multiple of 8) ----------------
__global__ void k_f32_to_bf16(const float* __restrict__ in, bf16* __restrict__ out, int n) {
  int i = (blockIdx.x * blockDim.x + threadIdx.x) * 8;
  if (i >= n) return;
  float4 a = *(const float4*)(in + i);
  float4 b = *(const float4*)(in + i + 4);
  bf16x8 o;
  o[0] = (bf16)a.x; o[1] = (bf16)a.y; o[2] = (bf16)a.z; o[3] = (bf16)a.w;
  o[4] = (bf16)b.x; o[5] = (bf16)b.y; o[6] = (bf16)b.z; o[7] = (bf16)b.w;
  *(bf16x8*)(out + i) = o;
}

// ---------------- transpose f32[R][C] -> bf16[C][R] ----------------
__global__ void k_transpose_f32_bf16(const float* __restrict__ in, bf16* __restrict__ out,
                                     int R, int C) {
  __shared__ float tile[32][33];
  int c0 = blockIdx.x * 32, r0 = blockIdx.y * 32;
  int tx = threadIdx.x & 31, ty = threadIdx.x >> 5;  // 32 x 8
#pragma unroll
  for (int i = 0; i < 32; i += 8)
    tile[ty + i][tx] = in[(size_t)(r0 + ty + i) * C + c0 + tx];
  __syncthreads();
#pragma unroll
  for (int i = 0; i < 32; i += 8)
    out[(size_t)(c0 + ty + i) * R + r0 + tx] = (bf16)tile[tx][ty + i];
}

// ---------------- RoPE tables: cos/sin [T][32] fp32 ----------------
__global__ void k_rope_tables(float* __restrict__ cosT, float* __restrict__ sinT, int total) {
  int i = blockIdx.x * blockDim.x + threadIdx.x;
  if (i >= total) return;
  int t = i >> 5, j = i & 31;
  float inv = powf(10000.0f, -(float)j * (1.0f / 32.0f));
  float f = (float)t * inv;
  cosT[i] = cosf(f);
  sinT[i] = sinf(f);
}

// ---------------- RoPE q,k: qkv[4096][3072] -> qr,kr [B][H][T][64] ----------------
// q is pre-scaled by 0.125 (exact pow2 in bf16) so flash needs no scale.
__global__ void k_rope_qk(const bf16* __restrict__ qkv, const float* __restrict__ cosT,
                          const float* __restrict__ sinT, bf16* __restrict__ qr,
                          bf16* __restrict__ kr) {
  int i = blockIdx.x * blockDim.x + threadIdx.x;  // B*T*H*32 = 2^21
  int j = i & 31;
  int h = (i >> 5) & 15;
  int t = (i >> 9) & 2047;
  int b = i >> 20;
  size_t base = (size_t)(b * 2048 + t) * 3072;
  float c = cosT[t * 32 + j], s = sinT[t * 32 + j];
  float qlo = (float)qkv[base + h * 64 + j];
  float qhi = (float)qkv[base + h * 64 + j + 32];
  float klo = (float)qkv[base + 1024 + h * 64 + j];
  float khi = (float)qkv[base + 1024 + h * 64 + j + 32];
  size_t ob = ((size_t)(b * 16 + h) * 2048 + t) * 64;
  qr[ob + j]      = (bf16)((qlo * c - qhi * s) * 0.125f);
  qr[ob + j + 32] = (bf16)((qhi * c + qlo * s) * 0.125f);
  kr[ob + j]      = (bf16)(klo * c - khi * s);
  kr[ob + j + 32] = (bf16)(khi * c + klo * s);
}

// ---------------- V scatter: qkv v-section -> vt [B][H][64][T] ----------------
__global__ void k_v_scatter(const bf16* __restrict__ qkv, bf16* __restrict__ vt) {
  __shared__ bf16 tile[64][66];
  int bh = blockIdx.y;           // 0..31
  int t0 = blockIdx.x * 64;
  int b = bh >> 4, h = bh & 15;
  int tt = threadIdx.x >> 2, c4 = (threadIdx.x & 3) * 16;
  const bf16* src = qkv + (size_t)(b * 2048 + t0 + tt) * 3072 + 2048 + h * 64 + c4;
  bf16x8 v0 = *(const bf16x8*)src;
  bf16x8 v1 = *(const bf16x8*)(src + 8);
#pragma unroll
  for (int j = 0; j < 8; j++) { tile[tt][c4 + j] = v0[j]; tile[tt][c4 + 8 + j] = v1[j]; }
  __syncthreads();
  int d = threadIdx.x >> 2, tc0 = (threadIdx.x & 3) * 16;
  bf16x8 o0, o1;
#pragma unroll
  for (int j = 0; j < 8; j++) { o0[j] = tile[tc0 + j][d]; o1[j] = tile[tc0 + 8 + j][d]; }
  bf16* dst = vt + ((size_t)bh * 64 + d) * 2048 + t0 + tc0;
  *(bf16x8*)dst = o0;
  *(bf16x8*)(dst + 8) = o1;
}

// ---------------- GEMM (m97 structure): C[M][N] = A[M][K] * Bt[N][K]^T ----------------
template <int OUTF32>
__global__ __launch_bounds__(256) void k_gemm_bt(const bf16* __restrict__ A,
                                                 const bf16* __restrict__ Bt,
                                                 float* __restrict__ Cf, bf16* __restrict__ Cb,
                                                 int M, int N, int K) {
  __shared__ __align__(16) bf16 sA[128 * 64];
  __shared__ __align__(16) bf16 sB[128 * 64];
  int m0 = blockIdx.y * 128, n0 = blockIdx.x * 128;
  int t = threadIdx.x, lane = t & 63, w = t >> 6;
  int wr = w >> 1, wc = w & 1;
  int lr = lane & 15, q2 = lane >> 4;
  int srow8 = lane >> 3, pc8 = lane & 7;
  f32x4 acc[4][4] = {};
  for (int k0 = 0; k0 < K; k0 += 64) {
#pragma unroll
    for (int is = 0; is < 4; is++) {
      int r = w * 32 + is * 8 + srow8;
      int lc = pc8 ^ (r & 7);
      G2L(A + (size_t)(m0 + r) * K + k0 + lc * 8, &sA[(w * 32 + is * 8) * 64]);
    }
#pragma unroll
    for (int is = 0; is < 4; is++) {
      int r = w * 32 + is * 8 + srow8;
      int lc = pc8 ^ (r & 7);
      G2L(Bt + (size_t)(n0 + r) * K + k0 + lc * 8, &sB[(w * 32 + is * 8) * 64]);
    }
    __syncthreads();
#pragma unroll
    for (int ch = 0; ch < 2; ch++) {
      bf16x8 af[4], bfr[4];
#pragma unroll
      for (int i = 0; i < 4; i++) {
        int r = wr * 64 + i * 16 + lr;
        af[i] = *(const bf16x8*)&sA[r * 64 + (((ch * 4 + q2) ^ (r & 7)) * 8)];
      }
#pragma unroll
      for (int i = 0; i < 4; i++) {
        int r = wc * 64 + i * 16 + lr;
        bfr[i] = *(const bf16x8*)&sB[r * 64 + (((ch * 4 + q2) ^ (r & 7)) * 8)];
      }
#pragma unroll
      for (int mi = 0; mi < 4; mi++)
#pragma unroll
        for (int ni = 0; ni < 4; ni++)
          acc[mi][ni] = __builtin_amdgcn_mfma_f32_16x16x32_bf16(af[mi], bfr[ni], acc[mi][ni], 0, 0, 0);
    }
    __syncthreads();
  }
  int row_base = m0 + wr * 64, col_base = n0 + wc * 64;
#pragma unroll
  for (int mi = 0; mi < 4; mi++)
#pragma unroll
    for (int ni = 0; ni < 4; ni++) {
      int col = col_base + ni * 16 + lr;
#pragma unroll
      for (int r = 0; r < 4; r++) {
        int row = row_base + mi * 16 + q2 * 4 + r;
        float v = acc[mi][ni][r];
        if (OUTF32) Cf[(size_t)row * N + col] = v;
        else        Cb[(size_t)row * N + col] = (bf16)v;
      }
    }
}

// ---------------- causal flash attention: QBLK=64, 2 waves, permlane P path ----------------
// qr,kr: [BH][T][64]; vt: [BH][64][T]; out (attn): [B][T][1024] bf16
// Grid (32,32): qb = (by&16) ? 31-bx : bx  -> co-resident blocks per CU sum to 66 iters.
// Wave w owns q [qb*64 + w*32, +32). Swapped MFMA: S^T = K*Q^T so q is lane-local (col=q31).
__global__ __launch_bounds__(128) void k_flash(const bf16* __restrict__ qr,
                                               const bf16* __restrict__ kr,
                                               const bf16* __restrict__ vt,
                                               bf16* __restrict__ out) {
  const int T = 2048;
  int bx = blockIdx.x;            // 0..31
  int by = blockIdx.y;            // 0..31  (= bh)
  int qb = (by & 16) ? (31 - bx) : bx;
  int bh = by;
  int b = bh >> 4, h = bh & 15;
  __shared__ __align__(16) bf16 sK[2][64 * 64];
  __shared__ __align__(16) bf16 sV[2][64 * 64];
  int t = threadIdx.x, lane = t & 63, w = t >> 6;  // w in {0,1}
  int q31 = lane & 31, hi = lane >> 5;
  int srow8 = lane >> 3, pc8 = lane & 7;

  const bf16* Kbh = kr + (size_t)bh * T * 64;
  const bf16* Vbh = vt + (size_t)bh * 64 * T;

  int nk = qb + 1;
  int qwb = qb * 64 + w * 32;
  int qg = qwb + q31;

  // Q B-frags (pre-scaled by 1/8): lane holds q-col qg, d = ks*16 + hi*8 + 0..7
  const bf16* qrow = qr + ((size_t)bh * T + qg) * 64 + hi * 8;
  bf16x8 qf[4];
#pragma unroll
  for (int ks = 0; ks < 4; ks++) qf[ks] = *(const bf16x8*)(qrow + ks * 16);
  f32x16 o0 = {}, o1 = {};
  float m = -1e30f, l = 0.f;

  auto stage = [&](int buf, int kt) {
#pragma unroll
    for (int is = 0; is < 4; is++) {
      int r = w * 32 + is * 8 + srow8;
      int lc = pc8 ^ (r & 7);
      G2L(Kbh + (size_t)(kt * 64 + r) * 64 + lc * 8, &sK[buf][(w * 32 + is * 8) * 64]);
    }
#pragma unroll
    for (int is = 0; is < 4; is++) {
      int d = w * 32 + is * 8 + srow8;
      int lc = pc8 ^ (d & 7);
      G2L(Vbh + (size_t)d * T + kt * 64 + lc * 8, &sV[buf][(w * 32 + is * 8) * 64]);
    }
  };

  stage(0, 0);
  for (int kt = 0; kt < nk; kt++) {
    int buf = kt & 1;
    if (kt + 1 < nk) {
      stage(buf ^ 1, kt + 1);
      asm volatile("s_waitcnt vmcnt(8)" ::: "memory");  // this tile's 8 loads done; next 8 in flight
    } else {
      asm volatile("s_waitcnt vmcnt(0)" ::: "memory");
    }
    __builtin_amdgcn_s_barrier();
    asm volatile("" ::: "memory");
    __builtin_amdgcn_sched_barrier(0);
    const bf16* Kb = &sK[buf][0];
    const bf16* Vb = &sV[buf][0];
    // ---- S^T = K Q^T : two 32x32 tiles (kb), K-dim d=64 in 4 steps ----
    f32x16 s[2];
#pragma unroll
    for (int kb = 0; kb < 2; kb++) {
      f32x16 a = {};
      int krow = kb * 32 + q31;
#pragma unroll
      for (int ks = 0; ks < 4; ks++) {
        int ch = (ks * 2 + hi) ^ (krow & 7);
        bf16x8 kf = *(const bf16x8*)&Kb[krow * 64 + ch * 8];
        a = __builtin_amdgcn_mfma_f32_32x32x16_bf16(kf, qf[ks], a, 0, 0, 0);
      }
      s[kb] = a;
    }
    // ---- causal mask: only the diagonal tile needs it ----
    if (kt == qb) {
      int thr = qg - kt * 64;  // mask if k_local > thr
#pragma unroll
      for (int kb = 0; kb < 2; kb++)
#pragma unroll
        for (int r = 0; r < 16; r++) {
          int koff = kb * 32 + (r & 3) + 8 * (r >> 2) + 4 * hi;
          if (koff > thr) s[kb][r] = -1e30f;
        }
    }
    // ---- lane-local online softmax (q = qg; halves exchange via xor-32) ----
    float px = -1e30f;
#pragma unroll
    for (int kb = 0; kb < 2; kb++)
#pragma unroll
      for (int r = 0; r < 16; r++) px = fmaxf(px, s[kb][r]);
    px = fmaxf(px, __shfl_xor(px, 32, 64));
    float mn = fmaxf(m, px);
    float alpha = __expf(m - mn);
    m = mn;
    float rs = 0.f;
#pragma unroll
    for (int kb = 0; kb < 2; kb++)
#pragma unroll
      for (int r = 0; r < 16; r++) {
        float p = __expf(s[kb][r] - m);
        s[kb][r] = p;
        rs += p;
      }
    rs += __shfl_xor(rs, 32, 64);
    l = l * alpha + rs;
    // ---- P -> PV B-frags in-register: cvt_pk pairs + permlane32_swap ----
    // s[kb][r] holds P[k = kb*32 + (r&3)+8*(r>>2)+4*hi][q=qg]. Frag(ks) needs
    // k = ks*16 + hi*8 + j. Swapping word g0 with word g1 across lane halves
    // yields frag words for both halves simultaneously (T12).
    int pw[4][4];
#pragma unroll
    for (int kb = 0; kb < 2; kb++) {
      int wd[8];
#pragma unroll
      for (int g = 0; g < 4; g++) {
        bf16x2 a, c;
        a[0] = (bf16)s[kb][4 * g + 0]; a[1] = (bf16)s[kb][4 * g + 1];
        c[0] = (bf16)s[kb][4 * g + 2]; c[1] = (bf16)s[kb][4 * g + 3];
        wd[2 * g]     = __builtin_bit_cast(int, a);
        wd[2 * g + 1] = __builtin_bit_cast(int, c);
      }
      asm volatile("v_permlane32_swap_b32 %0, %1" : "+v"(wd[0]), "+v"(wd[2]));
      asm volatile("v_permlane32_swap_b32 %0, %1" : "+v"(wd[1]), "+v"(wd[3]));
      asm volatile("v_permlane32_swap_b32 %0, %1" : "+v"(wd[4]), "+v"(wd[6]));
      asm volatile("v_permlane32_swap_b32 %0, %1" : "+v"(wd[5]), "+v"(wd[7]));
      pw[2 * kb][0] = wd[0]; pw[2 * kb][1] = wd[1];
      pw[2 * kb][2] = wd[2]; pw[2 * kb][3] = wd[3];
      pw[2 * kb + 1][0] = wd[4]; pw[2 * kb + 1][1] = wd[5];
      pw[2 * kb + 1][2] = wd[6]; pw[2 * kb + 1][3] = wd[7];
    }
    // ---- rescale O ----
#pragma unroll
    for (int r = 0; r < 16; r++) { o0[r] *= alpha; o1[r] *= alpha; }
    // ---- O^T += V^T P^T : two 32x32 tiles (d), K-dim k=64 in 4 steps ----
#pragma unroll
    for (int ks = 0; ks < 4; ks++) {
      i32x4 pv = {pw[ks][0], pw[ks][1], pw[ks][2], pw[ks][3]};
      bf16x8 pb = __builtin_bit_cast(bf16x8, pv);
      {
        int drow = q31;
        int ch = (ks * 2 + hi) ^ (drow & 7);
        bf16x8 vf = *(const bf16x8*)&Vb[drow * 64 + ch * 8];
        o0 = __builtin_amdgcn_mfma_f32_32x32x16_bf16(vf, pb, o0, 0, 0, 0);
      }
      {
        int drow = 32 + q31;
        int ch = (ks * 2 + hi) ^ (drow & 7);
        bf16x8 vf = *(const bf16x8*)&Vb[drow * 64 + ch * 8];
        o1 = __builtin_amdgcn_mfma_f32_32x32x16_bf16(vf, pb, o1, 0, 0, 0);
      }
    }
    asm volatile("" ::: "memory");
    __builtin_amdgcn_s_barrier();  // compute done; next stage may overwrite buf^1
    asm volatile("" ::: "memory");
  }
  // ---- epilogue: O^T[d][qg] -> out[b][qg][h*64+d], b64 stores ----
  float linv = 1.0f / l;
  bf16* orow = out + ((size_t)b * T + qg) * 1024 + h * 64;
#pragma unroll
  for (int g = 0; g < 4; g++) {
    bf16x4 v0, v1;
#pragma unroll
    for (int j = 0; j < 4; j++) {
      v0[j] = (bf16)(o0[4 * g + j] * linv);
      v1[j] = (bf16)(o1[4 * g + j] * linv);
    }
    *(bf16x4*)&orow[8 * g + 4 * hi]      = v0;
    *(bf16x4*)&orow[32 + 8 * g + 4 * hi] = v1;
  }
}

// ---------------- launch ----------------
extern "C" void kernel_launch(void* const* d_in, const int* in_sizes, int n_in,
                              void* d_out, int out_size, void* d_ws, size_t ws_size,
                              hipStream_t stream) {
  const float* x     = (const float*)d_in[0];
  const float* Wqkv  = (const float*)d_in[1];
  const float* Wproj = (const float*)d_in[2];
  float* outp = (float*)d_out;
  const int B = 2, T = 2048, C = 1024;
  const int M = B * T;  // 4096

  char* ws = (char*)d_ws;
  size_t off = 0;
  auto alloc = [&](size_t bytes) {
    void* p = ws + off;
    off += (bytes + 255) & ~(size_t)255;
    return p;
  };
  bf16* xb     = (bf16*)alloc((size_t)M * C * 2);
  bf16* wqkvt  = (bf16*)alloc((size_t)3 * C * C * 2);
  bf16* wprojt = (bf16*)alloc((size_t)C * C * 2);
  float* cosT  = (float*)alloc((size_t)T * 32 * 4);
  float* sinT  = (float*)alloc((size_t)T * 32 * 4);
  bf16* qkv    = (bf16*)alloc((size_t)M * 3 * C * 2);
  bf16* qr     = (bf16*)alloc((size_t)M * C * 2);
  bf16* kr     = (bf16*)alloc((size_t)M * C * 2);
  bf16* vt     = (bf16*)alloc((size_t)M * C * 2);
  bf16* attn   = qkv;  // alias: qkv dead after rope/v_scatter

  k_f32_to_bf16<<<dim3(M * C / 8 / 256), dim3(256), 0, stream>>>(x, xb, M * C);
  k_transpose_f32_bf16<<<dim3(3 * C / 32, C / 32), dim3(256), 0, stream>>>(Wqkv, wqkvt, C, 3 * C);
  k_transpose_f32_bf16<<<dim3(C / 32, C / 32), dim3(256), 0, stream>>>(Wproj, wprojt, C, C);
  k_rope_tables<<<dim3(T * 32 / 256), dim3(256), 0, stream>>>(cosT, sinT, T * 32);
  k_gemm_bt<0><<<dim3(3 * C / 128, M / 128), dim3(256), 0, stream>>>(xb, wqkvt, (float*)nullptr, qkv, M, 3 * C, C);
  k_rope_qk<<<dim3((B * T * 16 * 32) / 256), dim3(256), 0, stream>>>(qkv, cosT, sinT, qr, kr);
  k_v_scatter<<<dim3(T / 64, 32), dim3(256), 0, stream>>>(qkv, vt);
  k_flash<<<dim3(32, 32), dim3(128), 0, stream>>>(qr, kr, vt, attn);
  k_gemm_bt<1><<<dim3(C / 128, M / 128), dim3(256), 0, stream>>>(attn, wprojt, outp, (bf16*)nullptr, M, C, C);
}

// Round 6
// 140.789 us; speedup vs baseline: 1.0868x; 1.0685x over previous
//
#include <hip/hip_runtime.h>
#include <cstdint>
#include <cstddef>

typedef __bf16 bf16;
typedef __bf16 bf16x2 __attribute__((ext_vector_type(2)));
typedef __bf16 bf16x4 __attribute__((ext_vector_type(4)));
typedef __bf16 bf16x8 __attribute__((ext_vector_type(8)));
typedef float  f32x4  __attribute__((ext_vector_type(4)));
typedef float  f32x16 __attribute__((ext_vector_type(16)));
typedef int    i32x4  __attribute__((ext_vector_type(4)));

// global -> LDS direct (16B/lane, dest = wave-uniform base + lane*16)
#define G2L(src, dst)                                                          \
  __builtin_amdgcn_global_load_lds(                                            \
      (const __attribute__((address_space(1))) unsigned int*)(src),            \
      (__attribute__((address_space(3))) unsigned int*)(dst), 16, 0, 0)

// ---------------- convert f32 -> bf16 (n multiple of 8) ----------------
__global__ void k_f32_to_bf16(const float* __restrict__ in, bf16* __restrict__ out, int n) {
  int i = (blockIdx.x * blockDim.x + threadIdx.x) * 8;
  if (i >= n) return;
  float4 a = *(const float4*)(in + i);
  float4 b = *(const float4*)(in + i + 4);
  bf16x8 o;
  o[0] = (bf16)a.x; o[1] = (bf16)a.y; o[2] = (bf16)a.z; o[3] = (bf16)a.w;
  o[4] = (bf16)b.x; o[5] = (bf16)b.y; o[6] = (bf16)b.z; o[7] = (bf16)b.w;
  *(bf16x8*)(out + i) = o;
}

// ---------------- transpose f32[R][C] -> bf16[C][R] ----------------
__global__ void k_transpose_f32_bf16(const float* __restrict__ in, bf16* __restrict__ out,
                                     int R, int C) {
  __shared__ float tile[32][33];
  int c0 = blockIdx.x * 32, r0 = blockIdx.y * 32;
  int tx = threadIdx.x & 31, ty = threadIdx.x >> 5;  // 32 x 8
#pragma unroll
  for (int i = 0; i < 32; i += 8)
    tile[ty + i][tx] = in[(size_t)(r0 + ty + i) * C + c0 + tx];
  __syncthreads();
#pragma unroll
  for (int i = 0; i < 32; i += 8)
    out[(size_t)(c0 + ty + i) * R + r0 + tx] = (bf16)tile[tx][ty + i];
}

// ---------------- RoPE tables: cos/sin [T][32] fp32 ----------------
__global__ void k_rope_tables(float* __restrict__ cosT, float* __restrict__ sinT, int total) {
  int i = blockIdx.x * blockDim.x + threadIdx.x;
  if (i >= total) return;
  int t = i >> 5, j = i & 31;
  float inv = powf(10000.0f, -(float)j * (1.0f / 32.0f));
  float f = (float)t * inv;
  cosT[i] = cosf(f);
  sinT[i] = sinf(f);
}

// ---------------- RoPE q,k: qkv[4096][3072] -> qr,kr [B][H][T][64] ----------------
// q is pre-scaled by 0.125 (exact pow2 in bf16) so flash needs no scale.
__global__ void k_rope_qk(const bf16* __restrict__ qkv, const float* __restrict__ cosT,
                          const float* __restrict__ sinT, bf16* __restrict__ qr,
                          bf16* __restrict__ kr) {
  int i = blockIdx.x * blockDim.x + threadIdx.x;  // B*T*H*32 = 2^21
  int j = i & 31;
  int h = (i >> 5) & 15;
  int t = (i >> 9) & 2047;
  int b = i >> 20;
  size_t base = (size_t)(b * 2048 + t) * 3072;
  float c = cosT[t * 32 + j], s = sinT[t * 32 + j];
  float qlo = (float)qkv[base + h * 64 + j];
  float qhi = (float)qkv[base + h * 64 + j + 32];
  float klo = (float)qkv[base + 1024 + h * 64 + j];
  float khi = (float)qkv[base + 1024 + h * 64 + j + 32];
  size_t ob = ((size_t)(b * 16 + h) * 2048 + t) * 64;
  qr[ob + j]      = (bf16)((qlo * c - qhi * s) * 0.125f);
  qr[ob + j + 32] = (bf16)((qhi * c + qlo * s) * 0.125f);
  kr[ob + j]      = (bf16)(klo * c - khi * s);
  kr[ob + j + 32] = (bf16)(khi * c + klo * s);
}

// ---------------- V scatter: qkv v-section -> vt [B][H][64][T] ----------------
__global__ void k_v_scatter(const bf16* __restrict__ qkv, bf16* __restrict__ vt) {
  __shared__ bf16 tile[64][66];
  int bh = blockIdx.y;           // 0..31
  int t0 = blockIdx.x * 64;
  int b = bh >> 4, h = bh & 15;
  int tt = threadIdx.x >> 2, c4 = (threadIdx.x & 3) * 16;
  const bf16* src = qkv + (size_t)(b * 2048 + t0 + tt) * 3072 + 2048 + h * 64 + c4;
  bf16x8 v0 = *(const bf16x8*)src;
  bf16x8 v1 = *(const bf16x8*)(src + 8);
#pragma unroll
  for (int j = 0; j < 8; j++) { tile[tt][c4 + j] = v0[j]; tile[tt][c4 + 8 + j] = v1[j]; }
  __syncthreads();
  int d = threadIdx.x >> 2, tc0 = (threadIdx.x & 3) * 16;
  bf16x8 o0, o1;
#pragma unroll
  for (int j = 0; j < 8; j++) { o0[j] = tile[tc0 + j][d]; o1[j] = tile[tc0 + 8 + j][d]; }
  bf16* dst = vt + ((size_t)bh * 64 + d) * 2048 + t0 + tc0;
  *(bf16x8*)dst = o0;
  *(bf16x8*)(dst + 8) = o1;
}

// ---------------- GEMM (m97 structure): C[M][N] = A[M][K] * Bt[N][K]^T ----------------
template <int OUTF32>
__global__ __launch_bounds__(256) void k_gemm_bt(const bf16* __restrict__ A,
                                                 const bf16* __restrict__ Bt,
                                                 float* __restrict__ Cf, bf16* __restrict__ Cb,
                                                 int M, int N, int K) {
  __shared__ __align__(16) bf16 sA[128 * 64];
  __shared__ __align__(16) bf16 sB[128 * 64];
  int m0 = blockIdx.y * 128, n0 = blockIdx.x * 128;
  int t = threadIdx.x, lane = t & 63, w = t >> 6;
  int wr = w >> 1, wc = w & 1;
  int lr = lane & 15, q2 = lane >> 4;
  int srow8 = lane >> 3, pc8 = lane & 7;
  f32x4 acc[4][4] = {};
  for (int k0 = 0; k0 < K; k0 += 64) {
#pragma unroll
    for (int is = 0; is < 4; is++) {
      int r = w * 32 + is * 8 + srow8;
      int lc = pc8 ^ (r & 7);
      G2L(A + (size_t)(m0 + r) * K + k0 + lc * 8, &sA[(w * 32 + is * 8) * 64]);
    }
#pragma unroll
    for (int is = 0; is < 4; is++) {
      int r = w * 32 + is * 8 + srow8;
      int lc = pc8 ^ (r & 7);
      G2L(Bt + (size_t)(n0 + r) * K + k0 + lc * 8, &sB[(w * 32 + is * 8) * 64]);
    }
    __syncthreads();
#pragma unroll
    for (int ch = 0; ch < 2; ch++) {
      bf16x8 af[4], bfr[4];
#pragma unroll
      for (int i = 0; i < 4; i++) {
        int r = wr * 64 + i * 16 + lr;
        af[i] = *(const bf16x8*)&sA[r * 64 + (((ch * 4 + q2) ^ (r & 7)) * 8)];
      }
#pragma unroll
      for (int i = 0; i < 4; i++) {
        int r = wc * 64 + i * 16 + lr;
        bfr[i] = *(const bf16x8*)&sB[r * 64 + (((ch * 4 + q2) ^ (r & 7)) * 8)];
      }
#pragma unroll
      for (int mi = 0; mi < 4; mi++)
#pragma unroll
        for (int ni = 0; ni < 4; ni++)
          acc[mi][ni] = __builtin_amdgcn_mfma_f32_16x16x32_bf16(af[mi], bfr[ni], acc[mi][ni], 0, 0, 0);
    }
    __syncthreads();
  }
  int row_base = m0 + wr * 64, col_base = n0 + wc * 64;
#pragma unroll
  for (int mi = 0; mi < 4; mi++)
#pragma unroll
    for (int ni = 0; ni < 4; ni++) {
      int col = col_base + ni * 16 + lr;
#pragma unroll
      for (int r = 0; r < 4; r++) {
        int row = row_base + mi * 16 + q2 * 4 + r;
        float v = acc[mi][ni][r];
        if (OUTF32) Cf[(size_t)row * N + col] = v;
        else        Cb[(size_t)row * N + col] = (bf16)v;
      }
    }
}

// ---------------- causal flash attention: QBLK=64, 2 waves, longest-first grid ----------------
// qr,kr: [BH][T][64]; vt: [BH][64][T]; out (attn): [B][T][1024] bf16
// 1D grid of 1024: qb = 31 - id/32 (descending work), bh = id&31. HW backfills ->
// ~4 co-resident 2-wave blocks/CU throughout (greedy longest-first makespan).
__global__ __launch_bounds__(128) void k_flash(const bf16* __restrict__ qr,
                                               const bf16* __restrict__ kr,
                                               const bf16* __restrict__ vt,
                                               bf16* __restrict__ out) {
  const int T = 2048;
  int id = blockIdx.x;
  int qb = 31 - (id >> 5);
  int bh = id & 31;
  int b = bh >> 4, h = bh & 15;
  __shared__ __align__(16) bf16 sK[2][64 * 64];
  __shared__ __align__(16) bf16 sV[2][64 * 64];
  int t = threadIdx.x, lane = t & 63, w = t >> 6;  // w in {0,1}
  int q31 = lane & 31, hi = lane >> 5;
  int srow8 = lane >> 3, pc8 = lane & 7;

  const bf16* Kbh = kr + (size_t)bh * T * 64;
  const bf16* Vbh = vt + (size_t)bh * 64 * T;

  int nk = qb + 1;
  int qwb = qb * 64 + w * 32;
  int qg = qwb + q31;

  // Q B-frags (pre-scaled by 1/8): lane holds q-col qg, d = ks*16 + hi*8 + 0..7
  const bf16* qrow = qr + ((size_t)bh * T + qg) * 64 + hi * 8;
  bf16x8 qf[4];
#pragma unroll
  for (int ks = 0; ks < 4; ks++) qf[ks] = *(const bf16x8*)(qrow + ks * 16);
  f32x16 o0 = {}, o1 = {};
  float m = -1e30f, l = 0.f;

  auto stage = [&](int buf, int kt) {
#pragma unroll
    for (int is = 0; is < 4; is++) {
      int r = w * 32 + is * 8 + srow8;
      int lc = pc8 ^ (r & 7);
      G2L(Kbh + (size_t)(kt * 64 + r) * 64 + lc * 8, &sK[buf][(w * 32 + is * 8) * 64]);
    }
#pragma unroll
    for (int is = 0; is < 4; is++) {
      int d = w * 32 + is * 8 + srow8;
      int lc = pc8 ^ (d & 7);
      G2L(Vbh + (size_t)d * T + kt * 64 + lc * 8, &sV[buf][(w * 32 + is * 8) * 64]);
    }
  };

  stage(0, 0);
  for (int kt = 0; kt < nk; kt++) {
    int buf = kt & 1;
    if (kt + 1 < nk) {
      stage(buf ^ 1, kt + 1);
      asm volatile("s_waitcnt vmcnt(8)" ::: "memory");  // this tile's 8 loads done; next 8 in flight
    } else {
      asm volatile("s_waitcnt vmcnt(0)" ::: "memory");
    }
    __builtin_amdgcn_s_barrier();
    asm volatile("" ::: "memory");
    __builtin_amdgcn_sched_barrier(0);
    const bf16* Kb = &sK[buf][0];
    const bf16* Vb = &sV[buf][0];
    // ---- S^T = K Q^T : two 32x32 tiles (kb), K-dim d=64 in 4 steps ----
    f32x16 s[2];
    __builtin_amdgcn_s_setprio(1);
#pragma unroll
    for (int kb = 0; kb < 2; kb++) {
      f32x16 a = {};
      int krow = kb * 32 + q31;
#pragma unroll
      for (int ks = 0; ks < 4; ks++) {
        int ch = (ks * 2 + hi) ^ (krow & 7);
        bf16x8 kf = *(const bf16x8*)&Kb[krow * 64 + ch * 8];
        a = __builtin_amdgcn_mfma_f32_32x32x16_bf16(kf, qf[ks], a, 0, 0, 0);
      }
      s[kb] = a;
    }
    __builtin_amdgcn_s_setprio(0);
    // ---- causal mask: only the diagonal tile needs it ----
    if (kt == qb) {
      int thr = qg - kt * 64;  // mask if k_local > thr
#pragma unroll
      for (int kb = 0; kb < 2; kb++)
#pragma unroll
        for (int r = 0; r < 16; r++) {
          int koff = kb * 32 + (r & 3) + 8 * (r >> 2) + 4 * hi;
          if (koff > thr) s[kb][r] = -1e30f;
        }
    }
    // ---- lane-local online softmax: tree reductions (depth 5) ----
    float tm[16];
#pragma unroll
    for (int i = 0; i < 16; i++) tm[i] = fmaxf(s[0][i], s[1][i]);
#pragma unroll
    for (int st = 8; st > 0; st >>= 1)
#pragma unroll
      for (int i = 0; i < st; i++) tm[i] = fmaxf(tm[i], tm[i + st]);
    float px = tm[0];
    px = fmaxf(px, __shfl_xor(px, 32, 64));
    float mn = fmaxf(m, px);
    float alpha = __expf(m - mn);
    m = mn;
    float ts[16];
#pragma unroll
    for (int i = 0; i < 16; i++) {
      float p0 = __expf(s[0][i] - m);
      float p1 = __expf(s[1][i] - m);
      s[0][i] = p0;
      s[1][i] = p1;
      ts[i] = p0 + p1;
    }
#pragma unroll
    for (int st = 8; st > 0; st >>= 1)
#pragma unroll
      for (int i = 0; i < st; i++) ts[i] += ts[i + st];
    float rs = ts[0];
    rs += __shfl_xor(rs, 32, 64);
    l = l * alpha + rs;
    // ---- P -> PV B-frags in-register: cvt_pk pairs + permlane32_swap (T12) ----
    int pw[4][4];
#pragma unroll
    for (int kb = 0; kb < 2; kb++) {
      int wd[8];
#pragma unroll
      for (int g = 0; g < 4; g++) {
        bf16x2 a, c;
        a[0] = (bf16)s[kb][4 * g + 0]; a[1] = (bf16)s[kb][4 * g + 1];
        c[0] = (bf16)s[kb][4 * g + 2]; c[1] = (bf16)s[kb][4 * g + 3];
        wd[2 * g]     = __builtin_bit_cast(int, a);
        wd[2 * g + 1] = __builtin_bit_cast(int, c);
      }
      asm volatile("v_permlane32_swap_b32 %0, %1" : "+v"(wd[0]), "+v"(wd[2]));
      asm volatile("v_permlane32_swap_b32 %0, %1" : "+v"(wd[1]), "+v"(wd[3]));
      asm volatile("v_permlane32_swap_b32 %0, %1" : "+v"(wd[4]), "+v"(wd[6]));
      asm volatile("v_permlane32_swap_b32 %0, %1" : "+v"(wd[5]), "+v"(wd[7]));
      pw[2 * kb][0] = wd[0]; pw[2 * kb][1] = wd[1];
      pw[2 * kb][2] = wd[2]; pw[2 * kb][3] = wd[3];
      pw[2 * kb + 1][0] = wd[4]; pw[2 * kb + 1][1] = wd[5];
      pw[2 * kb + 1][2] = wd[6]; pw[2 * kb + 1][3] = wd[7];
    }
    // ---- rescale O ----
#pragma unroll
    for (int r = 0; r < 16; r++) { o0[r] *= alpha; o1[r] *= alpha; }
    // ---- O^T += V^T P^T : two 32x32 tiles (d), K-dim k=64 in 4 steps ----
    __builtin_amdgcn_s_setprio(1);
#pragma unroll
    for (int ks = 0; ks < 4; ks++) {
      i32x4 pv = {pw[ks][0], pw[ks][1], pw[ks][2], pw[ks][3]};
      bf16x8 pb = __builtin_bit_cast(bf16x8, pv);
      {
        int drow = q31;
        int ch = (ks * 2 + hi) ^ (drow & 7);
        bf16x8 vf = *(const bf16x8*)&Vb[drow * 64 + ch * 8];
        o0 = __builtin_amdgcn_mfma_f32_32x32x16_bf16(vf, pb, o0, 0, 0, 0);
      }
      {
        int drow = 32 + q31;
        int ch = (ks * 2 + hi) ^ (drow & 7);
        bf16x8 vf = *(const bf16x8*)&Vb[drow * 64 + ch * 8];
        o1 = __builtin_amdgcn_mfma_f32_32x32x16_bf16(vf, pb, o1, 0, 0, 0);
      }
    }
    __builtin_amdgcn_s_setprio(0);
    asm volatile("" ::: "memory");
    __builtin_amdgcn_s_barrier();  // compute done; next stage may overwrite buf^1
    asm volatile("" ::: "memory");
  }
  // ---- epilogue: O^T[d][qg] -> out[b][qg][h*64+d], b64 stores ----
  float linv = 1.0f / l;
  bf16* orow = out + ((size_t)b * T + qg) * 1024 + h * 64;
#pragma unroll
  for (int g = 0; g < 4; g++) {
    bf16x4 v0, v1;
#pragma unroll
    for (int j = 0; j < 4; j++) {
      v0[j] = (bf16)(o0[4 * g + j] * linv);
      v1[j] = (bf16)(o1[4 * g + j] * linv);
    }
    *(bf16x4*)&orow[8 * g + 4 * hi]      = v0;
    *(bf16x4*)&orow[32 + 8 * g + 4 * hi] = v1;
  }
}

// ---------------- launch ----------------
extern "C" void kernel_launch(void* const* d_in, const int* in_sizes, int n_in,
                              void* d_out, int out_size, void* d_ws, size_t ws_size,
                              hipStream_t stream) {
  const float* x     = (const float*)d_in[0];
  const float* Wqkv  = (const float*)d_in[1];
  const float* Wproj = (const float*)d_in[2];
  float* outp = (float*)d_out;
  const int B = 2, T = 2048, C = 1024;
  const int M = B * T;  // 4096

  char* ws = (char*)d_ws;
  size_t off = 0;
  auto alloc = [&](size_t bytes) {
    void* p = ws + off;
    off += (bytes + 255) & ~(size_t)255;
    return p;
  };
  bf16* xb     = (bf16*)alloc((size_t)M * C * 2);
  bf16* wqkvt  = (bf16*)alloc((size_t)3 * C * C * 2);
  bf16* wprojt = (bf16*)alloc((size_t)C * C * 2);
  float* cosT  = (float*)alloc((size_t)T * 32 * 4);
  float* sinT  = (float*)alloc((size_t)T * 32 * 4);
  bf16* qkv    = (bf16*)alloc((size_t)M * 3 * C * 2);
  bf16* qr     = (bf16*)alloc((size_t)M * C * 2);
  bf16* kr     = (bf16*)alloc((size_t)M * C * 2);
  bf16* vt     = (bf16*)alloc((size_t)M * C * 2);
  bf16* attn   = qkv;  // alias: qkv dead after rope/v_scatter

  k_f32_to_bf16<<<dim3(M * C / 8 / 256), dim3(256), 0, stream>>>(x, xb, M * C);
  k_transpose_f32_bf16<<<dim3(3 * C / 32, C / 32), dim3(256), 0, stream>>>(Wqkv, wqkvt, C, 3 * C);
  k_transpose_f32_bf16<<<dim3(C / 32, C / 32), dim3(256), 0, stream>>>(Wproj, wprojt, C, C);
  k_rope_tables<<<dim3(T * 32 / 256), dim3(256), 0, stream>>>(cosT, sinT, T * 32);
  k_gemm_bt<0><<<dim3(3 * C / 128, M / 128), dim3(256), 0, stream>>>(xb, wqkvt, (float*)nullptr, qkv, M, 3 * C, C);
  k_rope_qk<<<dim3((B * T * 16 * 32) / 256), dim3(256), 0, stream>>>(qkv, cosT, sinT, qr, kr);
  k_v_scatter<<<dim3(T / 64, 32), dim3(256), 0, stream>>>(qkv, vt);
  k_flash<<<dim3(1024), dim3(128), 0, stream>>>(qr, kr, vt, attn);
  k_gemm_bt<1><<<dim3(C / 128, M / 128), dim3(256), 0, stream>>>(attn, wprojt, outp, (bf16*)nullptr, M, C, C);
}